// Round 11
// baseline (316.248 us; speedup 1.0000x reference)
//
#include <hip/hip_runtime.h>
#include <hip/hip_bf16.h>

#define NUSERS 100000
#define NITEMS 50000
#define NN (NUSERS + NITEMS)      // 150000
#define NE 4000000
#define DIM 64
#define BQ 4096
#define NBIN ((NN + 255) >> 8)    // 586 bins of 256 rows
#define BINCAP 9216               // fixed slots/bin; mean w/ pads 7851, sigma ~90
#define EPB2 8192                 // edges per block in pass A (8/thread @ 1024)
#define PSH 14                    // column partition shift: 16384 rows = 2 MiB table
#define NP 10                     // ceil(150001 / 16384)

typedef unsigned short u16;
typedef unsigned int u32;
typedef float v2f __attribute__((ext_vector_type(2)));

__device__ __forceinline__ float bf2f(u16 u) {
    return __uint_as_float(((unsigned)u) << 16);
}
__device__ __forceinline__ u16 f2bf(float f) {
    unsigned x = __float_as_uint(f);
    return (u16)((x + 0x7FFFu + ((x >> 16) & 1u)) >> 16);   // RNE
}
// unpack uint4 (8 bf16) into 4 packed-f32 accumulates (v_pk_add_f32)
__device__ __forceinline__ void add8p(v2f* acc2, uint4 u) {
    acc2[0] += (v2f){__uint_as_float(u.x << 16), __uint_as_float(u.x & 0xffff0000u)};
    acc2[1] += (v2f){__uint_as_float(u.y << 16), __uint_as_float(u.y & 0xffff0000u)};
    acc2[2] += (v2f){__uint_as_float(u.z << 16), __uint_as_float(u.z & 0xffff0000u)};
    acc2[3] += (v2f){__uint_as_float(u.w << 16), __uint_as_float(u.w & 0xffff0000u)};
}
// 32-bit voffset + SGPR base load: offset = c*128 + dgoff, fits 25 bits
__device__ __forceinline__ uint4 ld_row(const char* __restrict__ base, int c, int dgoff) {
    u32 off = ((u32)c << 7) + (u32)dgoff;
    return *(const uint4*)(base + off);
}

// Shared row-sum core: cols preloaded in c_all (lane l holds col_s[start+l]),
// all G<=8 gathers issued before any add (max MLP). G wave-uniform.
__device__ __forceinline__ void rowsum_core(int start, int n8, int c_all,
                                            const int* __restrict__ col_s,
                                            const char* __restrict__ inb,
                                            int eslot, int dgoff, v2f* acc2) {
    int G = n8 >> 3;
    if (G <= 8) {
        int cg[8];
#pragma unroll
        for (int g = 0; g < 8; ++g)
            cg[g] = __shfl(c_all, (g << 3) + eslot, 64);
        uint4 v[8];
#pragma unroll
        for (int g = 0; g < 8; ++g)
            if (g < G) v[g] = ld_row(inb, cg[g], dgoff);
#pragma unroll
        for (int g = 0; g < 8; ++g)
            if (g < G) add8p(acc2, v[g]);
    } else {
        // fallback (deg > 64): pipelined loop over col_s
        int i = eslot;
        int c0 = col_s[start + i];
        uint4 v0 = ld_row(inb, c0, dgoff);
        for (i += 8; i < n8; i += 8) {
            int c1 = col_s[start + i];
            uint4 v1 = ld_row(inb, c1, dgoff);
            add8p(acc2, v0);
            v0 = v1;
        }
        add8p(acc2, v0);
    }
}

// wave-wide reduction over the 8 edge slots (pairs stay packed)
__device__ __forceinline__ void reduce_acc(v2f* acc2) {
#pragma unroll
    for (int off = 8; off <= 32; off <<= 1)
#pragma unroll
        for (int j = 0; j < 4; ++j) {
            v2f o;
            o.x = __shfl_xor(acc2[j].x, off, 64);
            o.y = __shfl_xor(acc2[j].y, off, 64);
            acc2[j] += o;
        }
}

// ---------------- init: bin cursors, m2 mask, sentinel rows ----------------
__global__ void k_init(int* __restrict__ bin_cur, u32* __restrict__ m2w,
                       u16* __restrict__ ea, u16* __restrict__ eb) {
    int t = blockIdx.x * blockDim.x + threadIdx.x;
    if (t < NBIN) bin_cur[t] = t * BINCAP;
    if (t < 37504) m2w[t] = 0;                 // zero 150016 bytes of m2
    if (t < 32) {                              // zero sentinel row NN in both tables
        ((u32*)(ea + (size_t)NN * DIM))[t] = 0;
        ((u32*)(eb + (size_t)NN * DIM))[t] = 0;
    }
}

// ---------------- Pass A: block-local counting sort, coalesced flush -------
// Packed u32: (row&255)<<24 | col  (col < 150000 < 2^24)
__global__ void __launch_bounds__(1024) k_binA2(
        const int* __restrict__ row, const int* __restrict__ col,
        int* __restrict__ bin_cur, u32* __restrict__ pairs, int E) {
    __shared__ u32 stage[EPB2];            // 32 KB
    __shared__ int hist[NBIN];
    __shared__ int base_l[NBIN];
    __shared__ int cbase[NBIN];
    __shared__ int lcur[NBIN];
    __shared__ int s[1024];
    int t = threadIdx.x;
    int base = blockIdx.x * EPB2;
    int lim = min(E - base, EPB2);

    if (t < NBIN) hist[t] = 0;
    __syncthreads();

    // P1: histogram by bin
    for (int i = t; i < lim; i += 1024)
        atomicAdd(&hist[row[base + i] >> 8], 1);
    __syncthreads();

    // P2: 1024-wide exclusive scan of hist + per-bin global chunk reserve
    int v = (t < NBIN) ? hist[t] : 0;
    s[t] = v;
    __syncthreads();
    for (int off = 1; off < 1024; off <<= 1) {
        int x = (t >= off) ? s[t - off] : 0;
        __syncthreads();
        s[t] += x;
        __syncthreads();
    }
    if (t < NBIN) {
        int excl = s[t] - v;
        base_l[t] = excl;
        lcur[t] = excl;
        cbase[t] = (v > 0) ? atomicAdd(&bin_cur[t], v) : 0;
    }
    __syncthreads();

    // P3: re-read edges (L2-hot), scatter into LDS stage ordered by bin
    for (int i = t; i < lim; i += 1024) {
        int r = row[base + i];
        int c = col[base + i];
        int pos = atomicAdd(&lcur[r >> 8], 1);
        stage[pos] = ((u32)(r & 255) << 24) | (u32)c;
    }
    __syncthreads();

    // P4: wave-cooperative flush, one bin per wave (coalesced stores)
    int wv = t >> 6;
    int lane = t & 63;
    for (int b = wv; b < NBIN; b += 16) {
        int h = hist[b];
        int lb = base_l[b];
        size_t gb = (size_t)cbase[b];
        for (int i = lane; i < h; i += 64)
            pairs[gb + i] = stage[lb + i];
    }
}

// ---------------- Pass B: per-bin (row, col-partition) sort; derives rs/deg;
// pads to 8; FUSED t0 = dis ⊙ emb0 conversion for this bin's rows. ------------
__global__ void __launch_bounds__(1024) k_binB(
        const u32* __restrict__ pairs, const int* __restrict__ bin_cur,
        int* __restrict__ col_s, int* __restrict__ rs, int* __restrict__ deg,
        const float* __restrict__ uemb, const float* __restrict__ itemb,
        u16* __restrict__ emb) {
    __shared__ int cnt2[256 * NP];   // 10 KB
    __shared__ int cur2[256 * NP];   // 10 KB
    __shared__ int pscan[256];
    __shared__ int degl[256];
    int b = blockIdx.x;
    int t = threadIdx.x;
    int base = b * BINCAP;
    int end = bin_cur[b];
    for (int i = t; i < 256 * NP; i += 1024) cnt2[i] = 0;
    __syncthreads();

    // P1: histogram by (row, partition) — contention spread over 2560 counters
    for (int i = base + t; i < end; i += 1024) {
        u32 p = pairs[i];
        int row = p >> 24;
        int c = (int)(p & 0x00FFFFFFu);
        atomicAdd(&cnt2[row * NP + (c >> PSH)], 1);
    }
    __syncthreads();

    // P2: per-row deg + pad; scan over rows; per-(row,partition) cursors
    int v = 0;
    if (t < 256) {
#pragma unroll
        for (int q = 0; q < NP; ++q) v += cnt2[t * NP + q];
    }
    int pv = (v + 7) & ~7;
    if (t < 256) pscan[t] = pv;
    __syncthreads();
    for (int off = 1; off < 256; off <<= 1) {
        int x = (t >= off && t < 256) ? pscan[t - off] : 0;
        __syncthreads();
        if (t < 256) pscan[t] += x;
        __syncthreads();
    }
    if (t < 256) {
        int rowstart = base + pscan[t] - pv;
        degl[t] = v;
        int r = (b << 8) + t;
        if (r < NN) {
            rs[r] = rowstart;
            deg[r] = v;
        }
        int acc = rowstart;
#pragma unroll
        for (int q = 0; q < NP; ++q) {
            cur2[t * NP + q] = acc;
            acc += cnt2[t * NP + q];
        }
        for (int i = v; i < pv; ++i) col_s[rowstart + i] = NN;   // sentinel pads
    }
    __syncthreads();

    // P3: scatter cols, partition-sorted within each row
    for (int i = base + t; i < end; i += 1024) {
        u32 p = pairs[i];
        int row = p >> 24;
        int c = (int)(p & 0x00FFFFFFu);
        int pos = atomicAdd(&cur2[row * NP + (c >> PSH)], 1);
        col_s[pos] = c;
    }

    // P4 (fused concat_t0): convert this bin's 256 rows to bf16 t0 = dis*emb0
    int r0 = b << 8;
    for (int sIdx = t; sIdx < 256 * 16; sIdx += 1024) {
        int rl = sIdx >> 4, j = sIdx & 15;
        int r = r0 + rl;
        if (r >= NN) continue;
        int d = degl[rl];
        float sc = (d > 0) ? (1.0f / sqrtf((float)d)) : 0.0f;
        float4 vv = (r < NUSERS) ? ((const float4*)uemb)[(size_t)r * 16 + j]
                                 : ((const float4*)itemb)[(size_t)(r - NUSERS) * 16 + j];
        ushort4 o;
        o.x = f2bf(sc * vv.x); o.y = f2bf(sc * vv.y);
        o.z = f2bf(sc * vv.z); o.w = f2bf(sc * vv.w);
        ((ushort4*)emb)[(size_t)r * 16 + j] = o;
    }
}

// mark rows needed for hop-2 output: one wave per query row, lanes scatter
__global__ void k_mark(const int* __restrict__ uid, const int* __restrict__ iid,
                       const int* __restrict__ rs, const int* __restrict__ deg,
                       const int* __restrict__ col_s, unsigned char* __restrict__ m2) {
    int q = (blockIdx.x * blockDim.x + threadIdx.x) >> 6;
    if (q >= 2 * BQ) return;
    int lane = threadIdx.x & 63;
    int r = (q < BQ) ? uid[q] : (NUSERS + iid[q - BQ]);
    if (lane == 0) m2[r] = 1;
    int s = rs[r], n = deg[r];
    for (int i = lane; i < n; i += 64) m2[col_s[s + i]] = 1;
}

// ---------------- SpMM in t-space: one wave per row ----------------
// t_{k+1}[r] = (1/deg[r]) * sum_{c in N(r)} t_k[c]
__global__ void k_spmm8(const int* __restrict__ rs, const int* __restrict__ deg,
                        const int* __restrict__ col_s, const u16* __restrict__ in,
                        u16* __restrict__ out, const unsigned char* __restrict__ mask) {
    int wid = (blockIdx.x * blockDim.x + threadIdx.x) >> 6;
    if (wid >= NN) return;
    if (mask && !mask[wid]) return;
    int lane = threadIdx.x & 63;
    int eslot = lane >> 3;
    int dg = lane & 7;
    int dgoff = dg << 4;
    int n = deg[wid];
    int start = rs[wid];
    int n8 = (n + 7) & ~7;
    int c_all = col_s[start + lane];           // preload up to 64 cols
    const char* inb = (const char*)in;
    v2f acc2[4] = {(v2f)0.f, (v2f)0.f, (v2f)0.f, (v2f)0.f};
    if (n8 > 0)
        rowsum_core(start, n8, c_all, col_s, inb, eslot, dgoff, acc2);
    reduce_acc(acc2);
    if (eslot == 0) {
        float s = (n > 0) ? (1.0f / (float)n) : 0.0f;  // dis[r]^2
        v2f vs = {s, s};
        u32 p[4];
#pragma unroll
        for (int j = 0; j < 4; ++j) {
            v2f r = acc2[j] * vs;
            __hip_bfloat162 h = __float22bfloat162_rn(make_float2(r.x, r.y));
            p[j] = *(u32*)&h;
        }
        ((uint4*)out)[(size_t)wid * 8 + dg] = make_uint4(p[0], p[1], p[2], p[3]);
    }
}

// hop-3 fused + e2 term: out = (out + sqrt(deg)*t2[r] + dis[r]*sum t2[c]) * 0.25
__global__ void k_spmm_out(const int* __restrict__ rs, const int* __restrict__ deg,
                           const int* __restrict__ col_s, const u16* __restrict__ in,
                           const int* __restrict__ uid, const int* __restrict__ iid,
                           float* __restrict__ out) {
    int q = (blockIdx.x * blockDim.x + threadIdx.x) >> 6;
    if (q >= 2 * BQ) return;
    int lane = threadIdx.x & 63;
    int eslot = lane >> 3;
    int dg = lane & 7;
    int dgoff = dg << 4;
    int b, r, off;
    if (q < BQ) { b = q; r = uid[q]; off = 0; }
    else { b = q - BQ; r = NUSERS + iid[q - BQ]; off = DIM; }
    int n = deg[r];
    int start = rs[r];
    int n8 = (n + 7) & ~7;
    int c_all = col_s[start + lane];
    const char* inb = (const char*)in;
    v2f acc2[4] = {(v2f)0.f, (v2f)0.f, (v2f)0.f, (v2f)0.f};
    if (n8 > 0)
        rowsum_core(start, n8, c_all, col_s, inb, eslot, dgoff, acc2);
    reduce_acc(acc2);
    if (eslot == 0) {
        float dr = (n > 0) ? (1.0f / sqrtf((float)n)) : 0.0f;   // dis[r]
        float sq = (n > 0) ? sqrtf((float)n) : 0.0f;            // 1/dis[r]
        uint4 tv = ld_row(inb, r, dgoff);                       // t2[r] slice
        float tr[8];
        tr[0] = __uint_as_float(tv.x << 16); tr[1] = __uint_as_float(tv.x & 0xffff0000u);
        tr[2] = __uint_as_float(tv.y << 16); tr[3] = __uint_as_float(tv.y & 0xffff0000u);
        tr[4] = __uint_as_float(tv.z << 16); tr[5] = __uint_as_float(tv.z & 0xffff0000u);
        tr[6] = __uint_as_float(tv.w << 16); tr[7] = __uint_as_float(tv.w & 0xffff0000u);
        float* o = out + (size_t)b * (2 * DIM) + off + dg * 8;
#pragma unroll
        for (int j = 0; j < 4; ++j) {
            o[2 * j]     = (o[2 * j]     + sq * tr[2 * j]     + dr * acc2[j].x) * 0.25f;
            o[2 * j + 1] = (o[2 * j + 1] + sq * tr[2 * j + 1] + dr * acc2[j].y) * 0.25f;
        }
    }
}

// ---------------- output gathers ----------------

__global__ void k_gather_init(const int* __restrict__ uid, const int* __restrict__ iid,
                              const float* __restrict__ u, const float* __restrict__ it,
                              float* __restrict__ out) {
    int t = blockIdx.x * blockDim.x + threadIdx.x;
    if (t >= BQ * DIM) return;
    int b = t >> 6;
    int d = t & 63;
    out[b * (2 * DIM) + d]       = u[(size_t)uid[b] * DIM + d];
    out[b * (2 * DIM) + DIM + d] = it[(size_t)iid[b] * DIM + d];
}

// out += sqrt(deg[r]) * t_k[r]   (emb_k = rdis ⊙ t_k)
__global__ void k_gather_add(const int* __restrict__ uid, const int* __restrict__ iid,
                             const int* __restrict__ deg, const u16* __restrict__ emb,
                             float* __restrict__ out) {
    int t = blockIdx.x * blockDim.x + threadIdx.x;
    if (t >= BQ * DIM) return;
    int b = t >> 6;
    int d = t & 63;
    int ru = uid[b];
    int ri = NUSERS + iid[b];
    int du = deg[ru], di = deg[ri];
    float su = (du > 0) ? sqrtf((float)du) : 0.0f;
    float si = (di > 0) ? sqrtf((float)di) : 0.0f;
    int ou = b * (2 * DIM) + d;
    int oi = ou + DIM;
    out[ou] = out[ou] + su * bf2f(emb[(size_t)ru * DIM + d]);
    out[oi] = out[oi] + si * bf2f(emb[(size_t)ri * DIM + d]);
}

// ---------------- launch ----------------

extern "C" void kernel_launch(void* const* d_in, const int* in_sizes, int n_in,
                              void* d_out, int out_size, void* d_ws, size_t ws_size,
                              hipStream_t stream) {
    const float* users_emb = (const float*)d_in[0];
    const float* items_emb = (const float*)d_in[1];
    const int*   edge_row  = (const int*)d_in[2];
    const int*   edge_col  = (const int*)d_in[3];
    const int*   user_id   = (const int*)d_in[4];
    const int*   item_ids  = (const int*)d_in[5];
    float* out = (float*)d_out;

    char* ws = (char*)d_ws;
    // byte layout (ends ~90.3 MB):
    int*   deg_i   = (int*)  (ws + 0);          // 600 KB
    int*   rs      = (int*)  (ws + 655360);     // 600 KB
    int*   bin_cur = (int*)  (ws + 1310720);    // 2.4 KB
    unsigned char* m2 = (unsigned char*)(ws + 1400000);  // 150 KB
    int*   col_s   = (int*)  (ws + 4194304);    // 586*9216*4 = 21.6 MB
    u32*   pairs   = (u32*)  (ws + 29360128);   // 21.6 MB
    u16*   emb_a   = (u16*)  (ws + 54525952);   // (NN+1)*64*2 = 19.2 MB
    u16*   emb_b   = (u16*)  (ws + 75497472);   // 19.2 MB

    // init cursors + m2 + sentinel rows
    k_init<<<147, 256, 0, stream>>>(bin_cur, (u32*)m2, emb_a, emb_b);

    // binned CSR build; pass B sorts (row, col-partition), derives deg/rs,
    // pads to x8, and emits the bf16 t0 table (fused concat)
    k_binA2<<<(NE + EPB2 - 1) / EPB2, 1024, 0, stream>>>(edge_row, edge_col, bin_cur,
                                                         pairs, NE);
    k_binB<<<NBIN, 1024, 0, stream>>>(pairs, bin_cur, col_s, rs, deg_i,
                                      users_emb, items_emb, emb_a);

    // layer-0 contribution (fp32 sources)
    k_gather_init<<<(BQ * DIM + 255) / 256, 256, 0, stream>>>(user_id, item_ids,
                                                              users_emb, items_emb, out);

    // mark rows whose hop-2 output is read (one wave per query row)
    k_mark<<<(2 * BQ + 3) / 4, 256, 0, stream>>>(user_id, item_ids, rs, deg_i, col_s, m2);

    const int spmm_blocks = (NN + 3) / 4;
    // hop 1: full
    k_spmm8<<<spmm_blocks, 256, 0, stream>>>(rs, deg_i, col_s, emb_a, emb_b,
                                             (const unsigned char*)nullptr);
    k_gather_add<<<(BQ * DIM + 255) / 256, 256, 0, stream>>>(user_id, item_ids, deg_i,
                                                             emb_b, out);
    // hop 2: masked
    k_spmm8<<<spmm_blocks, 256, 0, stream>>>(rs, deg_i, col_s, emb_b, emb_a, m2);
    // hop 3 fused with e2 gather: out = (out + sq*t2[r] + dr*sum)*0.25
    k_spmm_out<<<(2 * BQ + 3) / 4, 256, 0, stream>>>(rs, deg_i, col_s, emb_a,
                                                     user_id, item_ids, out);
}